// Round 8
// baseline (230.770 us; speedup 1.0000x reference)
//
#include <hip/hip_runtime.h>
#include <math.h>

// SCNCore: hidden = sigmoid((concept@Wci^T)*(x@Win^T) + (concept@Wcs^T)*(h@Wst^T))
//          i,f,o,cc = split(hidden,4); c_t = i*cc + f*c_state; h_t = o*tanh(c_t)
// B=1024, IN=H=1024, C=1000, 4H=4096. Inputs fp32, outputs fp32.
//
// R17 = R16 resubmit (previous round died to container-acquisition infra
// failure; no kernel signal). R16 rationale:
// A-in-registers. R13 refined post-mortem: LDS TOTAL BW (reads 2.68GB +
// writes 0.92GB = 3.6GB @ 69TB/s = 52us) == measured 51.2us -> R13 sits ON
// the LDS bandwidth floor. Cut traffic instead of rescheduling: the
// batch-side A tile has ZERO LDS reuse (written once, read once), and the
// A-fragment is 8 contiguous bf16 -> load global->reg directly (16B aligned;
// 4 quad-lanes cover a full 64B sector -> coalesced, L2-served). LDS stages
// ONLY W (2x cross-wn reuse). LDS traffic 3.6 -> 1.6 GB (23us floor).
// Waves: 2Mx2N of 32x32 tiles made of 16x16 frags with R13's exact
// conflict-free read algebra. Gates split across wn (wn0: i,f; wn1: o,cc)
// -> 8KiB LDS epilogue exchange reusing sB1, one extra barrier.
// Serial barrier loop, stage2g, conv_all, launcher: R13-verbatim.

typedef __bf16 bf16_t;
typedef __bf16 bf16x8 __attribute__((ext_vector_type(8)));
typedef float floatx4 __attribute__((ext_vector_type(4)));

#define THREADS 256

__device__ __forceinline__ void glds16(const void* g, void* l) {
  __builtin_amdgcn_global_load_lds((const __attribute__((address_space(1))) void*)g,
                                   (__attribute__((address_space(3))) void*)l,
                                   16, 0, 0);
}

// ============================ convert (R6 verbatim, single launch) ============================
__global__ __launch_bounds__(THREADS)
void conv_all(const float* __restrict__ x, const float* __restrict__ h,
              const float* __restrict__ Win, const float* __restrict__ Wst,
              const float* __restrict__ cpt, const float* __restrict__ Wci,
              const float* __restrict__ Wcs,
              bf16_t* __restrict__ xb, bf16_t* __restrict__ hb,
              bf16_t* __restrict__ Winb, bf16_t* __restrict__ Wstb,
              bf16_t* __restrict__ cb, bf16_t* __restrict__ Wcib,
              bf16_t* __restrict__ Wcsb)
{
  const int bid = blockIdx.x;
  if (bid < 5120) {
    const int c = bid * THREADS + threadIdx.x;
    const float* src; bf16_t* dst; int off;
    if      (c < 131072) { src = x;   dst = xb;   off = c; }
    else if (c < 262144) { src = h;   dst = hb;   off = c - 131072; }
    else if (c < 786432) { src = Win; dst = Winb; off = c - 262144; }
    else                 { src = Wst; dst = Wstb; off = c - 786432; }
    const size_t e0 = (size_t)off * 8;
    const float4 f0 = *(const float4*)(src + e0);
    const float4 f1 = *(const float4*)(src + e0 + 4);
    bf16x8 v;
    v[0] = (bf16_t)f0.x; v[1] = (bf16_t)f0.y; v[2] = (bf16_t)f0.z; v[3] = (bf16_t)f0.w;
    v[4] = (bf16_t)f1.x; v[5] = (bf16_t)f1.y; v[6] = (bf16_t)f1.z; v[7] = (bf16_t)f1.w;
    *(bf16x8*)(dst + e0) = v;
  } else {
    const int rid   = (bid - 5120) * 2 + (threadIdx.x >> 7);
    const int chunk = threadIdx.x & 127;
    const float* src; bf16_t* dst; int row;
    if      (rid < 1024) { src = cpt; dst = cb;   row = rid; }
    else if (rid < 5120) { src = Wci; dst = Wcib; row = rid - 1024; }
    else                 { src = Wcs; dst = Wcsb; row = rid - 5120; }
    bf16x8 v;
#pragma unroll
    for (int e = 0; e < 8; ++e) v[e] = (bf16_t)0.f;
    if (chunk < 125) {
      const size_t s0 = (size_t)row * 1000 + (size_t)chunk * 8;
      const float4 f0 = *(const float4*)(src + s0);
      const float4 f1 = *(const float4*)(src + s0 + 4);
      v[0] = (bf16_t)f0.x; v[1] = (bf16_t)f0.y; v[2] = (bf16_t)f0.z; v[3] = (bf16_t)f0.w;
      v[4] = (bf16_t)f1.x; v[5] = (bf16_t)f1.y; v[6] = (bf16_t)f1.z; v[7] = (bf16_t)f1.w;
    }
    *(bf16x8*)(dst + (size_t)row * 1024 + (size_t)chunk * 8) = v;
  }
}

// ============================ W staging (R5/R13 verbatim) ============================
// W tile: 64 rows x 128 B, gate-interleaved rows (tile row r -> W row
// (r>>4)*1024 + bx*16 + (r&15)), XOR-swizzled chunks
__device__ __forceinline__ void stage2g(const bf16_t* __restrict__ g, int bx, int kByte,
                                        char* s, int w, int lane) {
#pragma unroll
  for (int it = 0; it < 2; ++it) {
    const int flat = it * 4096 + w * 1024 + lane * 16;
    const int row  = flat >> 7;
    const int slot = (flat >> 4) & 7;
    const int srcb = kByte + ((slot ^ (row & 7)) << 4);
    const int wrow = ((row >> 4) << 10) + (bx << 4) + (row & 15);
    glds16((const char*)g + (size_t)wrow * 2048 + srcb, s + it * 4096 + w * 1024);
  }
}

// ============================ A fragments: global -> registers ============================
// Lane (l15, quad) fragment for kstep ks: A[row][ke + ks*32 + quad*8 .. +7]
// (identical algebra to R13's LDS af read, minus the LDS round-trip).
__device__ __forceinline__ void loadA(const bf16_t* __restrict__ g, size_t ar0, size_t ar1,
                                      int ke, int kq, bf16x8 (&a)[2][2]) {
  a[0][0] = *(const bf16x8*)(g + ar0 + ke + kq);
  a[0][1] = *(const bf16x8*)(g + ar0 + ke + 32 + kq);
  a[1][0] = *(const bf16x8*)(g + ar1 + ke + kq);
  a[1][1] = *(const bf16x8*)(g + ar1 + ke + 32 + kq);
}

// ============================ compute: A-reg x W-LDS ============================
// B-read pattern is R13's bfr verbatim (row = wn*32 + ni*16 + l15 keeps the
// same mod-8 structure -> 0 bank conflicts).
__device__ __forceinline__ void mfma_aw(const char* sB, int wn, int l15, int quad,
                                        const bf16x8 (&a)[2][2], floatx4 (&acc)[2][2]) {
#pragma unroll
  for (int ks = 0; ks < 2; ++ks) {
    bf16x8 b[2];
#pragma unroll
    for (int ni = 0; ni < 2; ++ni) {
      const int r = wn * 32 + ni * 16 + l15;
      const int c = (ks * 4 + quad) ^ (r & 7);
      b[ni] = *(const bf16x8*)(sB + r * 128 + c * 16);
    }
#pragma unroll
    for (int mi = 0; mi < 2; ++mi)
#pragma unroll
      for (int ni = 0; ni < 2; ++ni)
        acc[mi][ni] = __builtin_amdgcn_mfma_f32_16x16x32_bf16(a[mi][ks], b[ni],
                                                              acc[mi][ni], 0, 0, 0);
  }
}

// dual-W (Wci, Wcs) sharing the same A (concept) registers
__device__ __forceinline__ void mfma_aw2(const char* sB1, const char* sB2,
                                         int wn, int l15, int quad,
                                         const bf16x8 (&a)[2][2],
                                         floatx4 (&acc1)[2][2], floatx4 (&acc2)[2][2]) {
#pragma unroll
  for (int ks = 0; ks < 2; ++ks) {
    bf16x8 b1[2], b2[2];
#pragma unroll
    for (int ni = 0; ni < 2; ++ni) {
      const int r = wn * 32 + ni * 16 + l15;
      const int c = (ks * 4 + quad) ^ (r & 7);
      b1[ni] = *(const bf16x8*)(sB1 + r * 128 + c * 16);
      b2[ni] = *(const bf16x8*)(sB2 + r * 128 + c * 16);
    }
#pragma unroll
    for (int mi = 0; mi < 2; ++mi)
#pragma unroll
      for (int ni = 0; ni < 2; ++ni) {
        acc1[mi][ni] = __builtin_amdgcn_mfma_f32_16x16x32_bf16(a[mi][ks], b1[ni],
                                                               acc1[mi][ni], 0, 0, 0);
        acc2[mi][ni] = __builtin_amdgcn_mfma_f32_16x16x32_bf16(a[mi][ks], b2[ni],
                                                               acc2[mi][ni], 0, 0, 0);
      }
  }
}

// ============================ A-reg GEMM (R16) ============================
__global__ __launch_bounds__(THREADS, 4)
void scn_gemm_areg(const bf16_t* __restrict__ xb,   const bf16_t* __restrict__ hb,
                   const bf16_t* __restrict__ cb,
                   const bf16_t* __restrict__ Winb, const bf16_t* __restrict__ Wstb,
                   const bf16_t* __restrict__ Wcib, const bf16_t* __restrict__ Wcsb,
                   const float* __restrict__ cs, float* __restrict__ out)
{
  __shared__ __align__(16) char sB1[64 * 128];  // 8 KiB (W tile / epilogue exchange)
  __shared__ __align__(16) char sB2[64 * 128];  // 8 KiB  (16 KiB total)
  const int tid = threadIdx.x;
  const int w = tid >> 6, lane = tid & 63, l15 = lane & 15, quad = lane >> 4;
  const int wm = w >> 1, wn = w & 1;   // 2M x 2N waves, each 32 batch x 32 cols
  const int bx = blockIdx.x;           // 16 cols per gate; grid.x = 64
  const int M0 = blockIdx.y * 64;      // batch rows; grid.y = 16

  const size_t ar0 = (size_t)(M0 + wm * 32 + l15) * 1024;        // mi=0 A row
  const size_t ar1 = (size_t)(M0 + wm * 32 + 16 + l15) * 1024;   // mi=1 A row
  const int kq = quad * 8;

  floatx4 acc0[2][2], acc1[2][2], acc2[2][2];
  const floatx4 z = {0.f, 0.f, 0.f, 0.f};
#pragma unroll
  for (int mi = 0; mi < 2; ++mi)
#pragma unroll
    for (int ni = 0; ni < 2; ++ni) { acc0[mi][ni] = z; acc1[mi][ni] = z; acc2[mi][ni] = z; }

  // phase 1: xi = x @ Win^T -> acc0
  for (int i = 0; i < 16; ++i) {
    const int ke = i * 64;
    __syncthreads();
    bf16x8 a[2][2];
    loadA(xb, ar0, ar1, ke, kq, a);
    stage2g(Winb, bx, ke * 2, sB1, w, lane);
    __syncthreads();
    mfma_aw(sB1, wn, l15, quad, a, acc0);
  }
  // phase 2 (dual-W): gi -> acc1, gs -> acc2 (concept A-regs shared)
  for (int i = 0; i < 16; ++i) {
    const int ke = i * 64;
    __syncthreads();
    bf16x8 a[2][2];
    loadA(cb, ar0, ar1, ke, kq, a);
    stage2g(Wcib, bx, ke * 2, sB1, w, lane);
    stage2g(Wcsb, bx, ke * 2, sB2, w, lane);
    __syncthreads();
    mfma_aw2(sB1, sB2, wn, l15, quad, a, acc1, acc2);
  }
  // P = xi * gi (same C/D fragment layout); recycle acc1 for hs
#pragma unroll
  for (int mi = 0; mi < 2; ++mi)
#pragma unroll
    for (int ni = 0; ni < 2; ++ni) { acc0[mi][ni] = acc0[mi][ni] * acc1[mi][ni]; acc1[mi][ni] = z; }
  // phase 3: hs = h @ Wst^T -> acc1
  for (int i = 0; i < 16; ++i) {
    const int ke = i * 64;
    __syncthreads();
    bf16x8 a[2][2];
    loadA(hb, ar0, ar1, ke, kq, a);
    stage2g(Wstb, bx, ke * 2, sB1, w, lane);
    __syncthreads();
    mfma_aw(sB1, wn, l15, quad, a, acc1);
  }

  // ---- fused LSTM epilogue with cross-wn gate exchange ----
  // lane owns gates {2*wn + ni} for (batch row = M0+wm*32+mi*16+quad*4+r,
  // col = bx*16 + l15). wn0: {i,f}; wn1: {o,cc}. wn1 publishes via sB1.
  float sg[2][2][4];
#pragma unroll
  for (int mi = 0; mi < 2; ++mi)
#pragma unroll
    for (int ni = 0; ni < 2; ++ni)
#pragma unroll
      for (int r = 0; r < 4; ++r) {
        const float e = acc0[mi][ni][r] + acc2[mi][ni][r] * acc1[mi][ni][r];
        sg[mi][ni][r] = 1.f / (1.f + __expf(-e));
      }
  __syncthreads();                      // everyone done reading sB1 (ph3)
  float* sE = (float*)sB1;              // [ni][ (wm*2+mi)*16 + quad*4+r ][l15]
  if (wn == 1) {
#pragma unroll
    for (int mi = 0; mi < 2; ++mi)
#pragma unroll
      for (int ni = 0; ni < 2; ++ni)
#pragma unroll
        for (int r = 0; r < 4; ++r) {
          const int idx = ((wm * 2 + mi) * 16 + (quad * 4 + r)) * 16 + l15;
          sE[ni * 1024 + idx] = sg[mi][ni][r];
        }
  }
  __syncthreads();
  if (wn == 0) {
#pragma unroll
    for (int mi = 0; mi < 2; ++mi)
#pragma unroll
      for (int r = 0; r < 4; ++r) {
        const int idx = ((wm * 2 + mi) * 16 + (quad * 4 + r)) * 16 + l15;
        const float go = sE[idx];           // gate 2 (o)
        const float gc = sE[1024 + idx];    // gate 3 (cc)
        const int row = M0 + wm * 32 + mi * 16 + quad * 4 + r;
        const int col = (bx << 4) + l15;
        const float cst = cs[(size_t)row * 1024 + col];
        const float ct = sg[mi][0][r] * gc + sg[mi][1][r] * cst;  // i*cc + f*cs
        const float ht = go * tanhf(ct);
        out[(size_t)row * 1024 + col] = ht;
        out[(size_t)(1u << 20) + (size_t)row * 1024 + col] = ct;
      }
  }
}

// ============================ legacy fallback (R4, known-good) ============================
__device__ __forceinline__ void compute_block_l(const char* sA, const char* sB,
                                                int w, int l15, int quad,
                                                floatx4 (&acc)[2][4]) {
#pragma unroll
  for (int ks = 0; ks < 2; ++ks) {
    bf16x8 af[2], bfr[4];
#pragma unroll
    for (int mi = 0; mi < 2; ++mi) {
      const int r = w * 32 + mi * 16 + l15;
      const int c = (ks * 4 + quad) ^ (r & 7);
      af[mi] = *(const bf16x8*)(sA + r * 128 + c * 16);
    }
#pragma unroll
    for (int ni = 0; ni < 4; ++ni) {
      const int r = ni * 16 + l15;
      const int c = (ks * 4 + quad) ^ (r & 7);
      bfr[ni] = *(const bf16x8*)(sB + r * 128 + c * 16);
    }
#pragma unroll
    for (int mi = 0; mi < 2; ++mi)
#pragma unroll
      for (int ni = 0; ni < 4; ++ni)
        acc[mi][ni] = __builtin_amdgcn_mfma_f32_16x16x32_bf16(af[mi], bfr[ni], acc[mi][ni], 0, 0, 0);
  }
}

template<int ITERS>
__device__ __forceinline__ void stage_tile_f32(const char* __restrict__ g, int row0,
                                               int Kelems, int kBase, char* s, int tid)
{
#pragma unroll
  for (int it = 0; it < ITERS; ++it) {
    const int flat = it * 4096 + tid * 16;
    const int row  = flat >> 7;
    const int slot = (flat >> 4) & 7;
    const int eb   = kBase + ((slot ^ (row & 7)) << 3);
    bf16x8 v;
#pragma unroll
    for (int e = 0; e < 8; ++e) v[e] = (bf16_t)0.f;
    if (eb + 8 <= Kelems) {
      const size_t e0 = (size_t)(row0 + row) * (size_t)Kelems + (size_t)eb;
      const float4 f0 = *(const float4*)(g + e0 * 4);
      const float4 f1 = *(const float4*)(g + e0 * 4 + 16);
      v[0] = (bf16_t)f0.x; v[1] = (bf16_t)f0.y; v[2] = (bf16_t)f0.z; v[3] = (bf16_t)f0.w;
      v[4] = (bf16_t)f1.x; v[5] = (bf16_t)f1.y; v[6] = (bf16_t)f1.z; v[7] = (bf16_t)f1.w;
    }
    *(bf16x8*)(s + flat) = v;
  }
}

__device__ __forceinline__ void gemm_phase_legacy(
    const char* __restrict__ gA, int M0, const char* __restrict__ gW, int N0,
    int Kelems, char* sA, char* sB, int tid, floatx4 (&acc)[2][4])
{
  const int w = tid >> 6, lane = tid & 63, l15 = lane & 15, quad = lane >> 4;
  const int iters = (Kelems + 63) >> 6;
  for (int i = 0; i < iters; ++i) {
    const int kb = i * 64;
    __syncthreads();
    stage_tile_f32<4>(gA, M0, Kelems, kb, sA, tid);
    stage_tile_f32<2>(gW, N0, Kelems, kb, sB, tid);
    __syncthreads();
    compute_block_l(sA, sB, w, l15, quad, acc);
  }
}

__global__ __launch_bounds__(THREADS)
void scn_gemm_legacy(const char* __restrict__ x, const char* __restrict__ h,
                     const char* __restrict__ cpt,
                     const char* __restrict__ Win, const char* __restrict__ Wst,
                     const char* __restrict__ Wci, const char* __restrict__ Wcs,
                     bf16_t* __restrict__ hidden)
{
  __shared__ __align__(16) char sA[128 * 128];
  __shared__ __align__(16) char sB[64 * 128];
  const int tid = threadIdx.x;
  const int N0 = blockIdx.x * 64, M0 = blockIdx.y * 128;
  floatx4 acc0[2][4], acc1[2][4], acc2[2][4];
  const floatx4 z = {0.f, 0.f, 0.f, 0.f};
#pragma unroll
  for (int mi = 0; mi < 2; ++mi)
#pragma unroll
    for (int ni = 0; ni < 4; ++ni) { acc0[mi][ni] = z; acc1[mi][ni] = z; acc2[mi][ni] = z; }
  gemm_phase_legacy(x, M0, Win, N0, 1024, sA, sB, tid, acc0);
  gemm_phase_legacy(cpt, M0, Wci, N0, 1000, sA, sB, tid, acc1);
#pragma unroll
  for (int mi = 0; mi < 2; ++mi)
#pragma unroll
    for (int ni = 0; ni < 4; ++ni) { acc0[mi][ni] = acc0[mi][ni] * acc1[mi][ni]; acc1[mi][ni] = z; }
  gemm_phase_legacy(h, M0, Wst, N0, 1024, sA, sB, tid, acc1);
  gemm_phase_legacy(cpt, M0, Wcs, N0, 1000, sA, sB, tid, acc2);
  const int w = tid >> 6, lane = tid & 63, l15 = lane & 15, quad = lane >> 4;
#pragma unroll
  for (int mi = 0; mi < 2; ++mi)
#pragma unroll
    for (int ni = 0; ni < 4; ++ni)
#pragma unroll
      for (int r = 0; r < 4; ++r) {
        const float e = acc0[mi][ni][r] + acc1[mi][ni][r] * acc2[mi][ni][r];
        const float s = 1.f / (1.f + __expf(-e));
        const int row = M0 + w * 32 + mi * 16 + quad * 4 + r;
        const int col = N0 + ni * 16 + l15;
        hidden[(size_t)row * 4096 + col] = (bf16_t)s;
      }
}

__global__ __launch_bounds__(THREADS)
void scn_combine(const bf16_t* __restrict__ hidden, const float* __restrict__ cs,
                 float* __restrict__ out)
{
  const int t = blockIdx.x * THREADS + threadIdx.x;
  const size_t idx = (size_t)t * 8;
  const size_t b = idx >> 10, col = idx & 1023;
  const size_t hb = b * 4096 + col;
  const bf16x8 vi = *(const bf16x8*)(hidden + hb);
  const bf16x8 vf = *(const bf16x8*)(hidden + hb + 1024);
  const bf16x8 vo = *(const bf16x8*)(hidden + hb + 2048);
  const bf16x8 vc = *(const bf16x8*)(hidden + hb + 3072);
  const float4 a = *(const float4*)(cs + idx);
  const float4 d = *(const float4*)(cs + idx + 4);
  const float cv[8] = {a.x, a.y, a.z, a.w, d.x, d.y, d.z, d.w};
  float ht[8], ct[8];
#pragma unroll
  for (int e = 0; e < 8; ++e) {
    ct[e] = (float)vi[e] * (float)vc[e] + (float)vf[e] * cv[e];
    ht[e] = (float)vo[e] * tanhf(ct[e]);
  }
  *(float4*)(out + idx)     = make_float4(ht[0], ht[1], ht[2], ht[3]);
  *(float4*)(out + idx + 4) = make_float4(ht[4], ht[5], ht[6], ht[7]);
  float* outc = out + (1u << 20);
  *(float4*)(outc + idx)     = make_float4(ct[0], ct[1], ct[2], ct[3]);
  *(float4*)(outc + idx + 4) = make_float4(ct[4], ct[5], ct[6], ct[7]);
}

extern "C" void kernel_launch(void* const* d_in, const int* in_sizes, int n_in,
                              void* d_out, int out_size, void* d_ws, size_t ws_size,
                              hipStream_t stream) {
  (void)in_sizes; (void)n_in; (void)out_size;
  const float* x   = (const float*)d_in[0];
  const float* h   = (const float*)d_in[1];
  const float* cst = (const float*)d_in[2];
  const float* cpt = (const float*)d_in[3];
  const float* Win = (const float*)d_in[4];
  const float* Wst = (const float*)d_in[5];
  const float* Wci = (const float*)d_in[6];
  const float* Wcs = (const float*)d_in[7];
  float* out = (float*)d_out;
  const size_t MB = 1u << 20;

  if (ws_size >= 38 * MB) {
    char* ws = (char*)d_ws;
    bf16_t* xb   = (bf16_t*)(ws);            // 2 MiB
    bf16_t* hbuf = (bf16_t*)(ws + 2 * MB);   // 2 MiB
    bf16_t* cb   = (bf16_t*)(ws + 4 * MB);   // 2 MiB (K padded)
    bf16_t* Winb = (bf16_t*)(ws + 6 * MB);   // 8 MiB
    bf16_t* Wstb = (bf16_t*)(ws + 14 * MB);  // 8 MiB
    bf16_t* Wcib = (bf16_t*)(ws + 22 * MB);  // 8 MiB (K padded)
    bf16_t* Wcsb = (bf16_t*)(ws + 30 * MB);  // 8 MiB (K padded)
    conv_all<<<5120 + 4608, THREADS, 0, stream>>>(x, h, Win, Wst, cpt, Wci, Wcs,
                                                  xb, hbuf, Winb, Wstb, cb, Wcib, Wcsb);
    dim3 grid(64, 16);  // 64 gate-col groups (16 cols x 4 gates) x 16 batch tiles
    scn_gemm_areg<<<grid, THREADS, 0, stream>>>(xb, hbuf, cb, Winb, Wstb, Wcib, Wcsb,
                                                cst, out);
  } else {
    bf16_t* hidden = (bf16_t*)((char*)d_ws + 256);
    dim3 grid(4096 / 64, 1024 / 128);
    scn_gemm_legacy<<<grid, THREADS, 0, stream>>>(
        (const char*)x, (const char*)h, (const char*)cpt,
        (const char*)Win, (const char*)Wst, (const char*)Wci, (const char*)Wcs, hidden);
    scn_combine<<<(1024 * 1024 / 8) / THREADS, THREADS, 0, stream>>>(hidden, cst, out);
  }
}

// Round 9
// 182.894 us; speedup vs baseline: 1.2618x; 1.2618x over previous
//
#include <hip/hip_runtime.h>
#include <math.h>

// SCNCore: hidden = sigmoid((concept@Wci^T)*(x@Win^T) + (concept@Wcs^T)*(h@Wst^T))
//          i,f,o,cc = split(hidden,4); c_t = i*cc + f*c_state; h_t = o*tanh(c_t)
// B=1024, IN=H=1024, C=1000, 4H=4096. Inputs fp32, outputs fp32.
//
// R18: iteration-count attack. R16/R17 verdict: global->VGPR operand loads in
// this barrier loop cost 2.3x vs global_load_lds (119us vs 51us, both correct)
// -> ALL staging must be glds16. R9 (2.1GB LDS traffic) and R13 (3.4GB) both
// measure ~52us -> the shared constant is 48 barrier-drain iterations, not
// pure LDS BW. This round halves the ph1/ph3 iteration count by fusing them:
// one loop stages x-tile, h-tile, Win, Wst (4 x 8KiB = 32KiB, STILL 4
// blocks/CU — R11's fusion died at 80KiB/1 block) and computes xi AND hs per
// barrier-pair. Loop 2 = R13's dual-B concept pass verbatim. 48 -> 32 iters,
// traffic unchanged. Null result => R13 is LDS-BW-bound => roofline.
// Wave shape 16x64 (only conflict-free pattern), stage2g, epilogue math,
// conv_all, grid (64,16), launch_bounds(256,4): R13-verbatim.

typedef __bf16 bf16_t;
typedef __bf16 bf16x8 __attribute__((ext_vector_type(8)));
typedef float floatx4 __attribute__((ext_vector_type(4)));

#define THREADS 256

__device__ __forceinline__ void glds16(const void* g, void* l) {
  __builtin_amdgcn_global_load_lds((const __attribute__((address_space(1))) void*)g,
                                   (__attribute__((address_space(3))) void*)l,
                                   16, 0, 0);
}

// ============================ convert (R6 verbatim, single launch) ============================
__global__ __launch_bounds__(THREADS)
void conv_all(const float* __restrict__ x, const float* __restrict__ h,
              const float* __restrict__ Win, const float* __restrict__ Wst,
              const float* __restrict__ cpt, const float* __restrict__ Wci,
              const float* __restrict__ Wcs,
              bf16_t* __restrict__ xb, bf16_t* __restrict__ hb,
              bf16_t* __restrict__ Winb, bf16_t* __restrict__ Wstb,
              bf16_t* __restrict__ cb, bf16_t* __restrict__ Wcib,
              bf16_t* __restrict__ Wcsb)
{
  const int bid = blockIdx.x;
  if (bid < 5120) {
    const int c = bid * THREADS + threadIdx.x;
    const float* src; bf16_t* dst; int off;
    if      (c < 131072) { src = x;   dst = xb;   off = c; }
    else if (c < 262144) { src = h;   dst = hb;   off = c - 131072; }
    else if (c < 786432) { src = Win; dst = Winb; off = c - 262144; }
    else                 { src = Wst; dst = Wstb; off = c - 786432; }
    const size_t e0 = (size_t)off * 8;
    const float4 f0 = *(const float4*)(src + e0);
    const float4 f1 = *(const float4*)(src + e0 + 4);
    bf16x8 v;
    v[0] = (bf16_t)f0.x; v[1] = (bf16_t)f0.y; v[2] = (bf16_t)f0.z; v[3] = (bf16_t)f0.w;
    v[4] = (bf16_t)f1.x; v[5] = (bf16_t)f1.y; v[6] = (bf16_t)f1.z; v[7] = (bf16_t)f1.w;
    *(bf16x8*)(dst + e0) = v;
  } else {
    const int rid   = (bid - 5120) * 2 + (threadIdx.x >> 7);
    const int chunk = threadIdx.x & 127;
    const float* src; bf16_t* dst; int row;
    if      (rid < 1024) { src = cpt; dst = cb;   row = rid; }
    else if (rid < 5120) { src = Wci; dst = Wcib; row = rid - 1024; }
    else                 { src = Wcs; dst = Wcsb; row = rid - 5120; }
    bf16x8 v;
#pragma unroll
    for (int e = 0; e < 8; ++e) v[e] = (bf16_t)0.f;
    if (chunk < 125) {
      const size_t s0 = (size_t)row * 1000 + (size_t)chunk * 8;
      const float4 f0 = *(const float4*)(src + s0);
      const float4 f1 = *(const float4*)(src + s0 + 4);
      v[0] = (bf16_t)f0.x; v[1] = (bf16_t)f0.y; v[2] = (bf16_t)f0.z; v[3] = (bf16_t)f0.w;
      v[4] = (bf16_t)f1.x; v[5] = (bf16_t)f1.y; v[6] = (bf16_t)f1.z; v[7] = (bf16_t)f1.w;
    }
    *(bf16x8*)(dst + (size_t)row * 1024 + (size_t)chunk * 8) = v;
  }
}

// ============================ GEMM building blocks (R13 verbatim) ============================
// A tile: 64 rows x 128 B, XOR-swizzled chunks, contiguous rows M0..M0+63
__device__ __forceinline__ void stage2a(const bf16_t* __restrict__ g, int row0, int kByte,
                                        char* s, int w, int lane) {
#pragma unroll
  for (int it = 0; it < 2; ++it) {
    const int flat = it * 4096 + w * 1024 + lane * 16;
    const int row  = flat >> 7;
    const int slot = (flat >> 4) & 7;
    const int srcb = kByte + ((slot ^ (row & 7)) << 4);
    glds16((const char*)g + (size_t)(row0 + row) * 2048 + srcb, s + it * 4096 + w * 1024);
  }
}

// W tile: 64 rows x 128 B, gate-interleaved rows (tile row r -> W row
// (r>>4)*1024 + bx*16 + (r&15)), XOR-swizzled chunks
__device__ __forceinline__ void stage2g(const bf16_t* __restrict__ g, int bx, int kByte,
                                        char* s, int w, int lane) {
#pragma unroll
  for (int it = 0; it < 2; ++it) {
    const int flat = it * 4096 + w * 1024 + lane * 16;
    const int row  = flat >> 7;
    const int slot = (flat >> 4) & 7;
    const int srcb = kByte + ((slot ^ (row & 7)) << 4);
    const int wrow = ((row >> 4) << 10) + (bx << 4) + (row & 15);
    glds16((const char*)g + (size_t)wrow * 2048 + srcb, s + it * 4096 + w * 1024);
  }
}

// per-wave 16 rows x 64 cols (R13 verbatim)
__device__ __forceinline__ void compute_block64(const char* sA, const char* sB,
                                                int w, int l15, int quad,
                                                floatx4 (&acc)[4]) {
#pragma unroll
  for (int ks = 0; ks < 2; ++ks) {
    bf16x8 af, bfr[4];
    {
      const int r = w * 16 + l15;
      const int c = (ks * 4 + quad) ^ (r & 7);
      af = *(const bf16x8*)(sA + r * 128 + c * 16);
    }
#pragma unroll
    for (int ni = 0; ni < 4; ++ni) {
      const int r = ni * 16 + l15;
      const int c = (ks * 4 + quad) ^ (r & 7);
      bfr[ni] = *(const bf16x8*)(sB + r * 128 + c * 16);
    }
#pragma unroll
    for (int ni = 0; ni < 4; ++ni)
      acc[ni] = __builtin_amdgcn_mfma_f32_16x16x32_bf16(af, bfr[ni], acc[ni], 0, 0, 0);
  }
}

__device__ __forceinline__ void compute_block2_64(const char* sA, const char* sB1,
                                                  const char* sB2, int w, int l15, int quad,
                                                  floatx4 (&acc1)[4], floatx4 (&acc2)[4]) {
#pragma unroll
  for (int ks = 0; ks < 2; ++ks) {
    bf16x8 af, b1[4], b2[4];
    {
      const int r = w * 16 + l15;
      const int c = (ks * 4 + quad) ^ (r & 7);
      af = *(const bf16x8*)(sA + r * 128 + c * 16);
    }
#pragma unroll
    for (int ni = 0; ni < 4; ++ni) {
      const int r = ni * 16 + l15;
      const int c = (ks * 4 + quad) ^ (r & 7);
      b1[ni] = *(const bf16x8*)(sB1 + r * 128 + c * 16);
      b2[ni] = *(const bf16x8*)(sB2 + r * 128 + c * 16);
    }
#pragma unroll
    for (int ni = 0; ni < 4; ++ni) {
      acc1[ni] = __builtin_amdgcn_mfma_f32_16x16x32_bf16(af, b1[ni], acc1[ni], 0, 0, 0);
      acc2[ni] = __builtin_amdgcn_mfma_f32_16x16x32_bf16(af, b2[ni], acc2[ni], 0, 0, 0);
    }
  }
}

// ============================ fused-ph13 GEMM (R18) ============================
__global__ __launch_bounds__(THREADS, 4)
void scn_gemm_f13(const bf16_t* __restrict__ xb,   const bf16_t* __restrict__ hb,
                  const bf16_t* __restrict__ cb,
                  const bf16_t* __restrict__ Winb, const bf16_t* __restrict__ Wstb,
                  const bf16_t* __restrict__ Wcib, const bf16_t* __restrict__ Wcsb,
                  const float* __restrict__ cs, float* __restrict__ out)
{
  __shared__ __align__(16) char sA [64 * 128];  // 8 KiB (x / concept)
  __shared__ __align__(16) char sAh[64 * 128];  // 8 KiB (h)
  __shared__ __align__(16) char sB1[64 * 128];  // 8 KiB (Win / Wci)
  __shared__ __align__(16) char sB2[64 * 128];  // 8 KiB (Wst / Wcs)  (32 KiB total)
  const int tid = threadIdx.x;
  const int w = tid >> 6, lane = tid & 63, l15 = lane & 15, quad = lane >> 4;
  const int bx = blockIdx.x;           // 16 cols per gate; grid.x = 64
  const int M0 = blockIdx.y * 64;      // batch rows; grid.y = 16

  // acc0 = xi, acc1 = gi, acc2 = gs, acc3 = hs
  floatx4 acc0[4], acc1[4], acc2[4], acc3[4];
  const floatx4 z = {0.f, 0.f, 0.f, 0.f};
#pragma unroll
  for (int ni = 0; ni < 4; ++ni) { acc0[ni] = z; acc1[ni] = z; acc2[ni] = z; acc3[ni] = z; }

  // loop 1 (fused ph1+ph3): xi = x@Win^T -> acc0, hs = h@Wst^T -> acc3
  for (int i = 0; i < 16; ++i) {
    const int kb = i * 128;
    __syncthreads();
    stage2a(xb,   M0, kb, sA,  w, lane);
    stage2a(hb,   M0, kb, sAh, w, lane);
    stage2g(Winb, bx, kb, sB1, w, lane);
    stage2g(Wstb, bx, kb, sB2, w, lane);
    __syncthreads();
    compute_block64(sA,  sB1, w, l15, quad, acc0);
    compute_block64(sAh, sB2, w, l15, quad, acc3);
  }
  // loop 2 (dual-B, R13 ph2 verbatim): gi -> acc1, gs -> acc2
  for (int i = 0; i < 16; ++i) {
    const int kb = i * 128;
    __syncthreads();
    stage2a(cb,   M0, kb, sA,  w, lane);
    stage2g(Wcib, bx, kb, sB1, w, lane);
    stage2g(Wcsb, bx, kb, sB2, w, lane);
    __syncthreads();
    compute_block2_64(sA, sB1, sB2, w, l15, quad, acc1, acc2);
  }

  // fused LSTM epilogue: e = xi*gi + gs*hs; ni = gate {0:i,1:f,2:o,3:cc}
  // C/D layout: row = quad*4 + r, col = l15 (col-within-gate = bx*16 + l15)
#pragma unroll
  for (int r = 0; r < 4; ++r) {
    float g[4];
#pragma unroll
    for (int ni = 0; ni < 4; ++ni) {
      const float e = acc0[ni][r] * acc1[ni][r] + acc2[ni][r] * acc3[ni][r];
      g[ni] = 1.f / (1.f + __expf(-e));
    }
    const int row = M0 + w * 16 + quad * 4 + r;
    const int col = (bx << 4) + l15;
    const float cst = cs[(size_t)row * 1024 + col];
    const float ct = g[0] * g[3] + g[1] * cst;
    const float ht = g[2] * tanhf(ct);
    out[(size_t)row * 1024 + col] = ht;
    out[(size_t)(1u << 20) + (size_t)row * 1024 + col] = ct;
  }
}

// ============================ legacy fallback (R4, known-good) ============================
__device__ __forceinline__ void compute_block_l(const char* sA, const char* sB,
                                                int w, int l15, int quad,
                                                floatx4 (&acc)[2][4]) {
#pragma unroll
  for (int ks = 0; ks < 2; ++ks) {
    bf16x8 af[2], bfr[4];
#pragma unroll
    for (int mi = 0; mi < 2; ++mi) {
      const int r = w * 32 + mi * 16 + l15;
      const int c = (ks * 4 + quad) ^ (r & 7);
      af[mi] = *(const bf16x8*)(sA + r * 128 + c * 16);
    }
#pragma unroll
    for (int ni = 0; ni < 4; ++ni) {
      const int r = ni * 16 + l15;
      const int c = (ks * 4 + quad) ^ (r & 7);
      bfr[ni] = *(const bf16x8*)(sB + r * 128 + c * 16);
    }
#pragma unroll
    for (int mi = 0; mi < 2; ++mi)
#pragma unroll
      for (int ni = 0; ni < 4; ++ni)
        acc[mi][ni] = __builtin_amdgcn_mfma_f32_16x16x32_bf16(af[mi], bfr[ni], acc[mi][ni], 0, 0, 0);
  }
}

template<int ITERS>
__device__ __forceinline__ void stage_tile_f32(const char* __restrict__ g, int row0,
                                               int Kelems, int kBase, char* s, int tid)
{
#pragma unroll
  for (int it = 0; it < ITERS; ++it) {
    const int flat = it * 4096 + tid * 16;
    const int row  = flat >> 7;
    const int slot = (flat >> 4) & 7;
    const int eb   = kBase + ((slot ^ (row & 7)) << 3);
    bf16x8 v;
#pragma unroll
    for (int e = 0; e < 8; ++e) v[e] = (bf16_t)0.f;
    if (eb + 8 <= Kelems) {
      const size_t e0 = (size_t)(row0 + row) * (size_t)Kelems + (size_t)eb;
      const float4 f0 = *(const float4*)(g + e0 * 4);
      const float4 f1 = *(const float4*)(g + e0 * 4 + 16);
      v[0] = (bf16_t)f0.x; v[1] = (bf16_t)f0.y; v[2] = (bf16_t)f0.z; v[3] = (bf16_t)f0.w;
      v[4] = (bf16_t)f1.x; v[5] = (bf16_t)f1.y; v[6] = (bf16_t)f1.z; v[7] = (bf16_t)f1.w;
    }
    *(bf16x8*)(s + flat) = v;
  }
}

__device__ __forceinline__ void gemm_phase_legacy(
    const char* __restrict__ gA, int M0, const char* __restrict__ gW, int N0,
    int Kelems, char* sA, char* sB, int tid, floatx4 (&acc)[2][4])
{
  const int w = tid >> 6, lane = tid & 63, l15 = lane & 15, quad = lane >> 4;
  const int iters = (Kelems + 63) >> 6;
  for (int i = 0; i < iters; ++i) {
    const int kb = i * 64;
    __syncthreads();
    stage_tile_f32<4>(gA, M0, Kelems, kb, sA, tid);
    stage_tile_f32<2>(gW, N0, Kelems, kb, sB, tid);
    __syncthreads();
    compute_block_l(sA, sB, w, l15, quad, acc);
  }
}

__global__ __launch_bounds__(THREADS)
void scn_gemm_legacy(const char* __restrict__ x, const char* __restrict__ h,
                     const char* __restrict__ cpt,
                     const char* __restrict__ Win, const char* __restrict__ Wst,
                     const char* __restrict__ Wci, const char* __restrict__ Wcs,
                     bf16_t* __restrict__ hidden)
{
  __shared__ __align__(16) char sA[128 * 128];
  __shared__ __align__(16) char sB[64 * 128];
  const int tid = threadIdx.x;
  const int N0 = blockIdx.x * 64, M0 = blockIdx.y * 128;
  floatx4 acc0[2][4], acc1[2][4], acc2[2][4];
  const floatx4 z = {0.f, 0.f, 0.f, 0.f};
#pragma unroll
  for (int mi = 0; mi < 2; ++mi)
#pragma unroll
    for (int ni = 0; ni < 4; ++ni) { acc0[mi][ni] = z; acc1[mi][ni] = z; acc2[mi][ni] = z; }
  gemm_phase_legacy(x, M0, Win, N0, 1024, sA, sB, tid, acc0);
  gemm_phase_legacy(cpt, M0, Wci, N0, 1000, sA, sB, tid, acc1);
#pragma unroll
  for (int mi = 0; mi < 2; ++mi)
#pragma unroll
    for (int ni = 0; ni < 4; ++ni) { acc0[mi][ni] = acc0[mi][ni] * acc1[mi][ni]; acc1[mi][ni] = z; }
  gemm_phase_legacy(h, M0, Wst, N0, 1024, sA, sB, tid, acc1);
  gemm_phase_legacy(cpt, M0, Wcs, N0, 1000, sA, sB, tid, acc2);
  const int w = tid >> 6, lane = tid & 63, l15 = lane & 15, quad = lane >> 4;
#pragma unroll
  for (int mi = 0; mi < 2; ++mi)
#pragma unroll
    for (int ni = 0; ni < 4; ++ni)
#pragma unroll
      for (int r = 0; r < 4; ++r) {
        const float e = acc0[mi][ni][r] + acc1[mi][ni][r] * acc2[mi][ni][r];
        const float s = 1.f / (1.f + __expf(-e));
        const int row = M0 + w * 32 + mi * 16 + quad * 4 + r;
        const int col = N0 + ni * 16 + l15;
        hidden[(size_t)row * 4096 + col] = (bf16_t)s;
      }
}

__global__ __launch_bounds__(THREADS)
void scn_combine(const bf16_t* __restrict__ hidden, const float* __restrict__ cs,
                 float* __restrict__ out)
{
  const int t = blockIdx.x * THREADS + threadIdx.x;
  const size_t idx = (size_t)t * 8;
  const size_t b = idx >> 10, col = idx & 1023;
  const size_t hb = b * 4096 + col;
  const bf16x8 vi = *(const bf16x8*)(hidden + hb);
  const bf16x8 vf = *(const bf16x8*)(hidden + hb + 1024);
  const bf16x8 vo = *(const bf16x8*)(hidden + hb + 2048);
  const bf16x8 vc = *(const bf16x8*)(hidden + hb + 3072);
  const float4 a = *(const float4*)(cs + idx);
  const float4 d = *(const float4*)(cs + idx + 4);
  const float cv[8] = {a.x, a.y, a.z, a.w, d.x, d.y, d.z, d.w};
  float ht[8], ct[8];
#pragma unroll
  for (int e = 0; e < 8; ++e) {
    ct[e] = (float)vi[e] * (float)vc[e] + (float)vf[e] * cv[e];
    ht[e] = (float)vo[e] * tanhf(ct[e]);
  }
  *(float4*)(out + idx)     = make_float4(ht[0], ht[1], ht[2], ht[3]);
  *(float4*)(out + idx + 4) = make_float4(ht[4], ht[5], ht[6], ht[7]);
  float* outc = out + (1u << 20);
  *(float4*)(outc + idx)     = make_float4(ct[0], ct[1], ct[2], ct[3]);
  *(float4*)(outc + idx + 4) = make_float4(ct[4], ct[5], ct[6], ct[7]);
}

extern "C" void kernel_launch(void* const* d_in, const int* in_sizes, int n_in,
                              void* d_out, int out_size, void* d_ws, size_t ws_size,
                              hipStream_t stream) {
  (void)in_sizes; (void)n_in; (void)out_size;
  const float* x   = (const float*)d_in[0];
  const float* h   = (const float*)d_in[1];
  const float* cst = (const float*)d_in[2];
  const float* cpt = (const float*)d_in[3];
  const float* Win = (const float*)d_in[4];
  const float* Wst = (const float*)d_in[5];
  const float* Wci = (const float*)d_in[6];
  const float* Wcs = (const float*)d_in[7];
  float* out = (float*)d_out;
  const size_t MB = 1u << 20;

  if (ws_size >= 38 * MB) {
    char* ws = (char*)d_ws;
    bf16_t* xb   = (bf16_t*)(ws);            // 2 MiB
    bf16_t* hbuf = (bf16_t*)(ws + 2 * MB);   // 2 MiB
    bf16_t* cb   = (bf16_t*)(ws + 4 * MB);   // 2 MiB (K padded)
    bf16_t* Winb = (bf16_t*)(ws + 6 * MB);   // 8 MiB
    bf16_t* Wstb = (bf16_t*)(ws + 14 * MB);  // 8 MiB
    bf16_t* Wcib = (bf16_t*)(ws + 22 * MB);  // 8 MiB (K padded)
    bf16_t* Wcsb = (bf16_t*)(ws + 30 * MB);  // 8 MiB (K padded)
    conv_all<<<5120 + 4608, THREADS, 0, stream>>>(x, h, Win, Wst, cpt, Wci, Wcs,
                                                  xb, hbuf, Winb, Wstb, cb, Wcib, Wcsb);
    dim3 grid(64, 16);  // 64 gate-col groups (16 cols x 4 gates) x 16 batch tiles
    scn_gemm_f13<<<grid, THREADS, 0, stream>>>(xb, hbuf, cb, Winb, Wstb, Wcib, Wcsb,
                                               cst, out);
  } else {
    bf16_t* hidden = (bf16_t*)((char*)d_ws + 256);
    dim3 grid(4096 / 64, 1024 / 128);
    scn_gemm_legacy<<<grid, THREADS, 0, stream>>>(
        (const char*)x, (const char*)h, (const char*)cpt,
        (const char*)Win, (const char*)Wst, (const char*)Wci, (const char*)Wcs, hidden);
    scn_combine<<<(1024 * 1024 / 8) / THREADS, THREADS, 0, stream>>>(hidden, cst, out);
  }
}

// Round 10
// 171.644 us; speedup vs baseline: 1.3445x; 1.0655x over previous
//
#include <hip/hip_runtime.h>
#include <math.h>

// SCNCore: hidden = sigmoid((concept@Wci^T)*(x@Win^T) + (concept@Wcs^T)*(h@Wst^T))
//          i,f,o,cc = split(hidden,4); c_t = i*cc + f*c_state; h_t = o*tanh(c_t)
// B=1024, IN=H=1024, C=1000, 4H=4096. Inputs fp32, outputs fp32.
//
// R19: counted-vmcnt pipeline (T4), unconfounded. R18 showed the cost is
// exposed latency PER drain, not drain count. R13 geometry kept verbatim
// (64x64 block, 16x64 waves, grid (64,16), 4 blk/CU); LDS 32 KiB (R18 proved
// 4 blk/CU at 32K). The two independent streams x@Win / h@Wst interleave over
// STATIC buffer sets {sA,sB1}/{sAh,sB2}: each vmcnt(4) waits for loads issued
// one full compute phase earlier (h_t / x_{t+1} stay in flight under the
// MFMAs); vmcnt never 0 mid-loop; raw s_barrier (no implicit full drain);
// 4 barriers per 2 K-tiles = R13's rate. Write-after-read races guarded:
// every restage sits behind a barrier following its last reader.
// ph2 (concept dual-B) stays R13-serial. conv_all, epilogue, legacy: verbatim.

typedef __bf16 bf16_t;
typedef __bf16 bf16x8 __attribute__((ext_vector_type(8)));
typedef float floatx4 __attribute__((ext_vector_type(4)));

#define THREADS 256

__device__ __forceinline__ void glds16(const void* g, void* l) {
  __builtin_amdgcn_global_load_lds((const __attribute__((address_space(1))) void*)g,
                                   (__attribute__((address_space(3))) void*)l,
                                   16, 0, 0);
}

__device__ __forceinline__ void vmcnt_wait4() {
  asm volatile("s_waitcnt vmcnt(4)" ::: "memory");
  __builtin_amdgcn_sched_barrier(0);
}
__device__ __forceinline__ void vmcnt_wait0() {
  asm volatile("s_waitcnt vmcnt(0)" ::: "memory");
  __builtin_amdgcn_sched_barrier(0);
}

// ============================ convert (R6 verbatim, single launch) ============================
__global__ __launch_bounds__(THREADS)
void conv_all(const float* __restrict__ x, const float* __restrict__ h,
              const float* __restrict__ Win, const float* __restrict__ Wst,
              const float* __restrict__ cpt, const float* __restrict__ Wci,
              const float* __restrict__ Wcs,
              bf16_t* __restrict__ xb, bf16_t* __restrict__ hb,
              bf16_t* __restrict__ Winb, bf16_t* __restrict__ Wstb,
              bf16_t* __restrict__ cb, bf16_t* __restrict__ Wcib,
              bf16_t* __restrict__ Wcsb)
{
  const int bid = blockIdx.x;
  if (bid < 5120) {
    const int c = bid * THREADS + threadIdx.x;
    const float* src; bf16_t* dst; int off;
    if      (c < 131072) { src = x;   dst = xb;   off = c; }
    else if (c < 262144) { src = h;   dst = hb;   off = c - 131072; }
    else if (c < 786432) { src = Win; dst = Winb; off = c - 262144; }
    else                 { src = Wst; dst = Wstb; off = c - 786432; }
    const size_t e0 = (size_t)off * 8;
    const float4 f0 = *(const float4*)(src + e0);
    const float4 f1 = *(const float4*)(src + e0 + 4);
    bf16x8 v;
    v[0] = (bf16_t)f0.x; v[1] = (bf16_t)f0.y; v[2] = (bf16_t)f0.z; v[3] = (bf16_t)f0.w;
    v[4] = (bf16_t)f1.x; v[5] = (bf16_t)f1.y; v[6] = (bf16_t)f1.z; v[7] = (bf16_t)f1.w;
    *(bf16x8*)(dst + e0) = v;
  } else {
    const int rid   = (bid - 5120) * 2 + (threadIdx.x >> 7);
    const int chunk = threadIdx.x & 127;
    const float* src; bf16_t* dst; int row;
    if      (rid < 1024) { src = cpt; dst = cb;   row = rid; }
    else if (rid < 5120) { src = Wci; dst = Wcib; row = rid - 1024; }
    else                 { src = Wcs; dst = Wcsb; row = rid - 5120; }
    bf16x8 v;
#pragma unroll
    for (int e = 0; e < 8; ++e) v[e] = (bf16_t)0.f;
    if (chunk < 125) {
      const size_t s0 = (size_t)row * 1000 + (size_t)chunk * 8;
      const float4 f0 = *(const float4*)(src + s0);
      const float4 f1 = *(const float4*)(src + s0 + 4);
      v[0] = (bf16_t)f0.x; v[1] = (bf16_t)f0.y; v[2] = (bf16_t)f0.z; v[3] = (bf16_t)f0.w;
      v[4] = (bf16_t)f1.x; v[5] = (bf16_t)f1.y; v[6] = (bf16_t)f1.z; v[7] = (bf16_t)f1.w;
    }
    *(bf16x8*)(dst + (size_t)row * 1024 + (size_t)chunk * 8) = v;
  }
}

// ============================ GEMM building blocks (R13 verbatim) ============================
// A tile: 64 rows x 128 B, XOR-swizzled chunks, contiguous rows M0..M0+63
__device__ __forceinline__ void stage2a(const bf16_t* __restrict__ g, int row0, int kByte,
                                        char* s, int w, int lane) {
#pragma unroll
  for (int it = 0; it < 2; ++it) {
    const int flat = it * 4096 + w * 1024 + lane * 16;
    const int row  = flat >> 7;
    const int slot = (flat >> 4) & 7;
    const int srcb = kByte + ((slot ^ (row & 7)) << 4);
    glds16((const char*)g + (size_t)(row0 + row) * 2048 + srcb, s + it * 4096 + w * 1024);
  }
}

// W tile: 64 rows x 128 B, gate-interleaved rows (tile row r -> W row
// (r>>4)*1024 + bx*16 + (r&15)), XOR-swizzled chunks
__device__ __forceinline__ void stage2g(const bf16_t* __restrict__ g, int bx, int kByte,
                                        char* s, int w, int lane) {
#pragma unroll
  for (int it = 0; it < 2; ++it) {
    const int flat = it * 4096 + w * 1024 + lane * 16;
    const int row  = flat >> 7;
    const int slot = (flat >> 4) & 7;
    const int srcb = kByte + ((slot ^ (row & 7)) << 4);
    const int wrow = ((row >> 4) << 10) + (bx << 4) + (row & 15);
    glds16((const char*)g + (size_t)wrow * 2048 + srcb, s + it * 4096 + w * 1024);
  }
}

// per-wave 16 rows x 64 cols (R13 verbatim)
__device__ __forceinline__ void compute_block64(const char* sA, const char* sB,
                                                int w, int l15, int quad,
                                                floatx4 (&acc)[4]) {
#pragma unroll
  for (int ks = 0; ks < 2; ++ks) {
    bf16x8 af, bfr[4];
    {
      const int r = w * 16 + l15;
      const int c = (ks * 4 + quad) ^ (r & 7);
      af = *(const bf16x8*)(sA + r * 128 + c * 16);
    }
#pragma unroll
    for (int ni = 0; ni < 4; ++ni) {
      const int r = ni * 16 + l15;
      const int c = (ks * 4 + quad) ^ (r & 7);
      bfr[ni] = *(const bf16x8*)(sB + r * 128 + c * 16);
    }
#pragma unroll
    for (int ni = 0; ni < 4; ++ni)
      acc[ni] = __builtin_amdgcn_mfma_f32_16x16x32_bf16(af, bfr[ni], acc[ni], 0, 0, 0);
  }
}

__device__ __forceinline__ void compute_block2_64(const char* sA, const char* sB1,
                                                  const char* sB2, int w, int l15, int quad,
                                                  floatx4 (&acc1)[4], floatx4 (&acc2)[4]) {
#pragma unroll
  for (int ks = 0; ks < 2; ++ks) {
    bf16x8 af, b1[4], b2[4];
    {
      const int r = w * 16 + l15;
      const int c = (ks * 4 + quad) ^ (r & 7);
      af = *(const bf16x8*)(sA + r * 128 + c * 16);
    }
#pragma unroll
    for (int ni = 0; ni < 4; ++ni) {
      const int r = ni * 16 + l15;
      const int c = (ks * 4 + quad) ^ (r & 7);
      b1[ni] = *(const bf16x8*)(sB1 + r * 128 + c * 16);
      b2[ni] = *(const bf16x8*)(sB2 + r * 128 + c * 16);
    }
#pragma unroll
    for (int ni = 0; ni < 4; ++ni) {
      acc1[ni] = __builtin_amdgcn_mfma_f32_16x16x32_bf16(af, b1[ni], acc1[ni], 0, 0, 0);
      acc2[ni] = __builtin_amdgcn_mfma_f32_16x16x32_bf16(af, b2[ni], acc2[ni], 0, 0, 0);
    }
  }
}

// ============================ counted-vmcnt pipelined GEMM (R19) ============================
__global__ __launch_bounds__(THREADS, 4)
void scn_gemm_pipe(const bf16_t* __restrict__ xb,   const bf16_t* __restrict__ hb,
                   const bf16_t* __restrict__ cb,
                   const bf16_t* __restrict__ Winb, const bf16_t* __restrict__ Wstb,
                   const bf16_t* __restrict__ Wcib, const bf16_t* __restrict__ Wcsb,
                   const float* __restrict__ cs, float* __restrict__ out)
{
  __shared__ __align__(16) char sA [64 * 128];  // 8 KiB (x / concept)
  __shared__ __align__(16) char sAh[64 * 128];  // 8 KiB (h)
  __shared__ __align__(16) char sB1[64 * 128];  // 8 KiB (Win / Wci)
  __shared__ __align__(16) char sB2[64 * 128];  // 8 KiB (Wst / Wcs)  (32 KiB)
  const int tid = threadIdx.x;
  const int w = tid >> 6, lane = tid & 63, l15 = lane & 15, quad = lane >> 4;
  const int bx = blockIdx.x;           // 16 cols per gate; grid.x = 64
  const int M0 = blockIdx.y * 64;      // batch rows; grid.y = 16

  // acc0 = xi, acc1 = gi, acc2 = gs, acc3 = hs
  floatx4 acc0[4], acc1[4], acc2[4], acc3[4];
  const floatx4 z = {0.f, 0.f, 0.f, 0.f};
#pragma unroll
  for (int ni = 0; ni < 4; ++ni) { acc0[ni] = z; acc1[ni] = z; acc2[ni] = z; acc3[ni] = z; }

  // ---- pipelined ph1+ph3: x@Win -> acc0, h@Wst -> acc3 ----
  // prologue: issue x-tile 0 (4 loads/thread, stays in flight)
  stage2a(xb,   M0, 0, sA,  w, lane);
  stage2g(Winb, bx, 0, sB1, w, lane);
  for (int t = 0; t < 16; ++t) {
    const int kb = t * 128;
    __builtin_amdgcn_s_barrier();             // alpha: all waves done reading sAh/sB2 (t-1)
    stage2a(hb,   M0, kb, sAh, w, lane);      // +4 -> 8 in flight
    stage2g(Wstb, bx, kb, sB2, w, lane);
    vmcnt_wait4();                            // x_t done (oldest 4); h_t still flying
    __builtin_amdgcn_s_barrier();             // beta: everyone's x-stores visible
    compute_block64(sA, sB1, w, l15, quad, acc0);   // h_t hides under this
    __builtin_amdgcn_s_barrier();             // gamma: all done reading sA/sB1
    if (t < 15) {
      stage2a(xb,   M0, kb + 128, sA,  w, lane);    // +4 -> 8 in flight
      stage2g(Winb, bx, kb + 128, sB1, w, lane);
      vmcnt_wait4();                          // h_t done; x_{t+1} still flying
    } else {
      vmcnt_wait0();                          // only h_15 outstanding
    }
    __builtin_amdgcn_s_barrier();             // delta: everyone's h-stores visible
    compute_block64(sAh, sB2, w, l15, quad, acc3);  // x_{t+1} hides under this
  }

  // ---- ph2 (dual-B concept pass, R13-serial) ----
  for (int i = 0; i < 16; ++i) {
    const int kb = i * 128;
    __syncthreads();                          // also guards sB2 vs computeH(15)
    stage2a(cb,   M0, kb, sA,  w, lane);
    stage2g(Wcib, bx, kb, sB1, w, lane);
    stage2g(Wcsb, bx, kb, sB2, w, lane);
    __syncthreads();
    compute_block2_64(sA, sB1, sB2, w, l15, quad, acc1, acc2);
  }

  // fused LSTM epilogue: e = xi*gi + gs*hs; ni = gate {0:i,1:f,2:o,3:cc}
  // C/D layout: row = quad*4 + r, col = l15 (col-within-gate = bx*16 + l15)
#pragma unroll
  for (int r = 0; r < 4; ++r) {
    float g[4];
#pragma unroll
    for (int ni = 0; ni < 4; ++ni) {
      const float e = acc0[ni][r] * acc1[ni][r] + acc2[ni][r] * acc3[ni][r];
      g[ni] = 1.f / (1.f + __expf(-e));
    }
    const int row = M0 + w * 16 + quad * 4 + r;
    const int col = (bx << 4) + l15;
    const float cst = cs[(size_t)row * 1024 + col];
    const float ct = g[0] * g[3] + g[1] * cst;
    const float ht = g[2] * tanhf(ct);
    out[(size_t)row * 1024 + col] = ht;
    out[(size_t)(1u << 20) + (size_t)row * 1024 + col] = ct;
  }
}

// ============================ legacy fallback (R4, known-good) ============================
__device__ __forceinline__ void compute_block_l(const char* sA, const char* sB,
                                                int w, int l15, int quad,
                                                floatx4 (&acc)[2][4]) {
#pragma unroll
  for (int ks = 0; ks < 2; ++ks) {
    bf16x8 af[2], bfr[4];
#pragma unroll
    for (int mi = 0; mi < 2; ++mi) {
      const int r = w * 32 + mi * 16 + l15;
      const int c = (ks * 4 + quad) ^ (r & 7);
      af[mi] = *(const bf16x8*)(sA + r * 128 + c * 16);
    }
#pragma unroll
    for (int ni = 0; ni < 4; ++ni) {
      const int r = ni * 16 + l15;
      const int c = (ks * 4 + quad) ^ (r & 7);
      bfr[ni] = *(const bf16x8*)(sB + r * 128 + c * 16);
    }
#pragma unroll
    for (int mi = 0; mi < 2; ++mi)
#pragma unroll
      for (int ni = 0; ni < 4; ++ni)
        acc[mi][ni] = __builtin_amdgcn_mfma_f32_16x16x32_bf16(af[mi], bfr[ni], acc[mi][ni], 0, 0, 0);
  }
}

template<int ITERS>
__device__ __forceinline__ void stage_tile_f32(const char* __restrict__ g, int row0,
                                               int Kelems, int kBase, char* s, int tid)
{
#pragma unroll
  for (int it = 0; it < ITERS; ++it) {
    const int flat = it * 4096 + tid * 16;
    const int row  = flat >> 7;
    const int slot = (flat >> 4) & 7;
    const int eb   = kBase + ((slot ^ (row & 7)) << 3);
    bf16x8 v;
#pragma unroll
    for (int e = 0; e < 8; ++e) v[e] = (bf16_t)0.f;
    if (eb + 8 <= Kelems) {
      const size_t e0 = (size_t)(row0 + row) * (size_t)Kelems + (size_t)eb;
      const float4 f0 = *(const float4*)(g + e0 * 4);
      const float4 f1 = *(const float4*)(g + e0 * 4 + 16);
      v[0] = (bf16_t)f0.x; v[1] = (bf16_t)f0.y; v[2] = (bf16_t)f0.z; v[3] = (bf16_t)f0.w;
      v[4] = (bf16_t)f1.x; v[5] = (bf16_t)f1.y; v[6] = (bf16_t)f1.z; v[7] = (bf16_t)f1.w;
    }
    *(bf16x8*)(s + flat) = v;
  }
}

__device__ __forceinline__ void gemm_phase_legacy(
    const char* __restrict__ gA, int M0, const char* __restrict__ gW, int N0,
    int Kelems, char* sA, char* sB, int tid, floatx4 (&acc)[2][4])
{
  const int w = tid >> 6, lane = tid & 63, l15 = lane & 15, quad = lane >> 4;
  const int iters = (Kelems + 63) >> 6;
  for (int i = 0; i < iters; ++i) {
    const int kb = i * 64;
    __syncthreads();
    stage_tile_f32<4>(gA, M0, Kelems, kb, sA, tid);
    stage_tile_f32<2>(gW, N0, Kelems, kb, sB, tid);
    __syncthreads();
    compute_block_l(sA, sB, w, l15, quad, acc);
  }
}

__global__ __launch_bounds__(THREADS)
void scn_gemm_legacy(const char* __restrict__ x, const char* __restrict__ h,
                     const char* __restrict__ cpt,
                     const char* __restrict__ Win, const char* __restrict__ Wst,
                     const char* __restrict__ Wci, const char* __restrict__ Wcs,
                     bf16_t* __restrict__ hidden)
{
  __shared__ __align__(16) char sA[128 * 128];
  __shared__ __align__(16) char sB[64 * 128];
  const int tid = threadIdx.x;
  const int N0 = blockIdx.x * 64, M0 = blockIdx.y * 128;
  floatx4 acc0[2][4], acc1[2][4], acc2[2][4];
  const floatx4 z = {0.f, 0.f, 0.f, 0.f};
#pragma unroll
  for (int mi = 0; mi < 2; ++mi)
#pragma unroll
    for (int ni = 0; ni < 4; ++ni) { acc0[mi][ni] = z; acc1[mi][ni] = z; acc2[mi][ni] = z; }
  gemm_phase_legacy(x, M0, Win, N0, 1024, sA, sB, tid, acc0);
  gemm_phase_legacy(cpt, M0, Wci, N0, 1000, sA, sB, tid, acc1);
#pragma unroll
  for (int mi = 0; mi < 2; ++mi)
#pragma unroll
    for (int ni = 0; ni < 4; ++ni) { acc0[mi][ni] = acc0[mi][ni] * acc1[mi][ni]; acc1[mi][ni] = z; }
  gemm_phase_legacy(h, M0, Wst, N0, 1024, sA, sB, tid, acc1);
  gemm_phase_legacy(cpt, M0, Wcs, N0, 1000, sA, sB, tid, acc2);
  const int w = tid >> 6, lane = tid & 63, l15 = lane & 15, quad = lane >> 4;
#pragma unroll
  for (int mi = 0; mi < 2; ++mi)
#pragma unroll
    for (int ni = 0; ni < 4; ++ni)
#pragma unroll
      for (int r = 0; r < 4; ++r) {
        const float e = acc0[mi][ni][r] + acc1[mi][ni][r] * acc2[mi][ni][r];
        const float s = 1.f / (1.f + __expf(-e));
        const int row = M0 + w * 32 + mi * 16 + quad * 4 + r;
        const int col = N0 + ni * 16 + l15;
        hidden[(size_t)row * 4096 + col] = (bf16_t)s;
      }
}

__global__ __launch_bounds__(THREADS)
void scn_combine(const bf16_t* __restrict__ hidden, const float* __restrict__ cs,
                 float* __restrict__ out)
{
  const int t = blockIdx.x * THREADS + threadIdx.x;
  const size_t idx = (size_t)t * 8;
  const size_t b = idx >> 10, col = idx & 1023;
  const size_t hb = b * 4096 + col;
  const bf16x8 vi = *(const bf16x8*)(hidden + hb);
  const bf16x8 vf = *(const bf16x8*)(hidden + hb + 1024);
  const bf16x8 vo = *(const bf16x8*)(hidden + hb + 2048);
  const bf16x8 vc = *(const bf16x8*)(hidden + hb + 3072);
  const float4 a = *(const float4*)(cs + idx);
  const float4 d = *(const float4*)(cs + idx + 4);
  const float cv[8] = {a.x, a.y, a.z, a.w, d.x, d.y, d.z, d.w};
  float ht[8], ct[8];
#pragma unroll
  for (int e = 0; e < 8; ++e) {
    ct[e] = (float)vi[e] * (float)vc[e] + (float)vf[e] * cv[e];
    ht[e] = (float)vo[e] * tanhf(ct[e]);
  }
  *(float4*)(out + idx)     = make_float4(ht[0], ht[1], ht[2], ht[3]);
  *(float4*)(out + idx + 4) = make_float4(ht[4], ht[5], ht[6], ht[7]);
  float* outc = out + (1u << 20);
  *(float4*)(outc + idx)     = make_float4(ct[0], ct[1], ct[2], ct[3]);
  *(float4*)(outc + idx + 4) = make_float4(ct[4], ct[5], ct[6], ct[7]);
}

extern "C" void kernel_launch(void* const* d_in, const int* in_sizes, int n_in,
                              void* d_out, int out_size, void* d_ws, size_t ws_size,
                              hipStream_t stream) {
  (void)in_sizes; (void)n_in; (void)out_size;
  const float* x   = (const float*)d_in[0];
  const float* h   = (const float*)d_in[1];
  const float* cst = (const float*)d_in[2];
  const float* cpt = (const float*)d_in[3];
  const float* Win = (const float*)d_in[4];
  const float* Wst = (const float*)d_in[5];
  const float* Wci = (const float*)d_in[6];
  const float* Wcs = (const float*)d_in[7];
  float* out = (float*)d_out;
  const size_t MB = 1u << 20;

  if (ws_size >= 38 * MB) {
    char* ws = (char*)d_ws;
    bf16_t* xb   = (bf16_t*)(ws);            // 2 MiB
    bf16_t* hbuf = (bf16_t*)(ws + 2 * MB);   // 2 MiB
    bf16_t* cb   = (bf16_t*)(ws + 4 * MB);   // 2 MiB (K padded)
    bf16_t* Winb = (bf16_t*)(ws + 6 * MB);   // 8 MiB
    bf16_t* Wstb = (bf16_t*)(ws + 14 * MB);  // 8 MiB
    bf16_t* Wcib = (bf16_t*)(ws + 22 * MB);  // 8 MiB (K padded)
    bf16_t* Wcsb = (bf16_t*)(ws + 30 * MB);  // 8 MiB (K padded)
    conv_all<<<5120 + 4608, THREADS, 0, stream>>>(x, h, Win, Wst, cpt, Wci, Wcs,
                                                  xb, hbuf, Winb, Wstb, cb, Wcib, Wcsb);
    dim3 grid(64, 16);  // 64 gate-col groups (16 cols x 4 gates) x 16 batch tiles
    scn_gemm_pipe<<<grid, THREADS, 0, stream>>>(xb, hbuf, cb, Winb, Wstb, Wcib, Wcsb,
                                                cst, out);
  } else {
    bf16_t* hidden = (bf16_t*)((char*)d_ws + 256);
    dim3 grid(4096 / 64, 1024 / 128);
    scn_gemm_legacy<<<grid, THREADS, 0, stream>>>(
        (const char*)x, (const char*)h, (const char*)cpt,
        (const char*)Win, (const char*)Wst, (const char*)Wci, (const char*)Wcs, hidden);
    scn_combine<<<(1024 * 1024 / 8) / THREADS, THREADS, 0, stream>>>(hidden, cst, out);
  }
}